// Round 1
// baseline (2342.822 us; speedup 1.0000x reference)
//
#include <hip/hip_runtime.h>

// HSMSSD3D fused pipeline, fp32 baseline.
// B=4, C=D_MODEL=256, S=64 (3S=192 channels), spatial N = 16*64*64 = 65536.
//
// Stages:
//  k_gemm1   : BCdt_raw[b,192,N] = W_bcdt @ x + b_bcdt            (buf1)
//  k_stats   : rowwise online softmax stats (max,sumexp) of conv(dt)+b_dw
//  k_ab      : AB[b,s,n] = softmax(conv(dt))*conv(B_)              (conv fused)
//  k_hgemm   : partial h = x . AB^T   (k-chunked, partials in dead dt region)
//  k_hreduce : h[b,c,s] = sum partials
//  k_small   : hz -> h3 -> h4  (h4 written to d_out tail = 2nd output)
//  k_y       : y[b,c,n] = sum_s h4[b,c,s]*conv(C_)[b,s,n]          (conv fused)
//
// Note: softmax(dt + A[s]) == softmax(dt) (A constant per row) -> A unused.

#define NN 65536
#define DD 16
#define HH 64
#define WW 64
#define CCH 256
#define SS 64
#define TS3 192
#define BB 4

#define OFF_AB   50331648ull   // after buf1 (4*192*65536)
#define OFF_RMAX 67108864ull
#define OFF_RSUM 67109120ull
#define OFF_H    67109376ull
#define YTOT     67108864ull   // y element count in d_out

// -------------------- 4-wide depthwise 3x3x3 conv helper --------------------
__device__ __forceinline__ float4 conv4(const float* __restrict__ base,
                                        int d, int h, int w0,
                                        const float* __restrict__ cw) {
  float ax = 0.f, ay = 0.f, az = 0.f, aw = 0.f;
#pragma unroll
  for (int kd = 0; kd < 3; ++kd) {
    int dd = d + kd - 1;
    if (dd < 0 || dd >= DD) continue;
#pragma unroll
    for (int kh = 0; kh < 3; ++kh) {
      int hh = h + kh - 1;
      if (hh < 0 || hh >= HH) continue;
      const float* row = base + dd * 4096 + hh * 64 + w0;
      float4 m = *(const float4*)row;
      float l = (w0 > 0) ? row[-1] : 0.f;
      float r = (w0 < 60) ? row[4] : 0.f;
      float c0 = cw[kd * 9 + kh * 3 + 0];
      float c1 = cw[kd * 9 + kh * 3 + 1];
      float c2 = cw[kd * 9 + kh * 3 + 2];
      ax = fmaf(c0, l,   fmaf(c1, m.x, fmaf(c2, m.y, ax)));
      ay = fmaf(c0, m.x, fmaf(c1, m.y, fmaf(c2, m.z, ay)));
      az = fmaf(c0, m.y, fmaf(c1, m.z, fmaf(c2, m.w, az)));
      aw = fmaf(c0, m.z, fmaf(c1, m.w, fmaf(c2, r,   aw)));
    }
  }
  return make_float4(ax, ay, az, aw);
}

// -------------------- K1: BCdt_raw = W_bcdt @ x + b --------------------
// block: 64 n-cols x all 192 o (4 waves x 48 o each). W tile staged in LDS,
// x read straight from global (coalesced; L1 shares across the 4 waves).
__global__ __launch_bounds__(256) void k_gemm1(const float* __restrict__ x,
                                               const float* __restrict__ Wb,
                                               const float* __restrict__ bb,
                                               float* __restrict__ out) {
  __shared__ float wl[TS3][36];  // 36-stride: 16B-aligned rows, conflict-free
  const int tid = threadIdx.x;
  const int nloc = tid & 63;
  const int og = tid >> 6;
  const int b = blockIdx.y;
  const int n0 = blockIdx.x * 64;
  const float* xb = x + (size_t)b * CCH * NN + n0 + nloc;
  float acc[48];
#pragma unroll
  for (int i = 0; i < 48; ++i) acc[i] = 0.f;
  for (int c0 = 0; c0 < CCH; c0 += 32) {
#pragma unroll
    for (int i = 0; i < 24; ++i) {
      int fl = tid + i * 256;
      int o = fl >> 5, cc = fl & 31;
      wl[o][cc] = Wb[o * 256 + c0 + cc];
    }
    __syncthreads();
    float xv[32];
#pragma unroll
    for (int cc = 0; cc < 32; ++cc) xv[cc] = xb[(size_t)(c0 + cc) * NN];
    const int ob = og * 48;
#pragma unroll
    for (int i = 0; i < 48; ++i) {
      float a = acc[i];
      const float* wr = &wl[ob + i][0];
#pragma unroll
      for (int cc = 0; cc < 32; ++cc) a = fmaf(wr[cc], xv[cc], a);
      acc[i] = a;
    }
    __syncthreads();
  }
  const int ob = og * 48;
  float* op = out + (size_t)(b * TS3 + ob) * NN + n0 + nloc;
#pragma unroll
  for (int i = 0; i < 48; ++i) op[(size_t)i * NN] = acc[i] + bb[ob + i];
}

// -------------------- K2: online softmax stats over conv(dt) ---------------
__global__ __launch_bounds__(256) void k_stats(const float* __restrict__ buf1,
                                               const float* __restrict__ Wdw,
                                               const float* __restrict__ bdw,
                                               float* __restrict__ rmax,
                                               float* __restrict__ rsum) {
  const int s = blockIdx.x, b = blockIdx.y, t = threadIdx.x;
  const int ch = 2 * SS + s;  // dt band
  const float* base = buf1 + (size_t)(b * TS3 + ch) * NN;
  float cw[27];
#pragma unroll
  for (int k = 0; k < 27; ++k) cw[k] = Wdw[ch * 27 + k];
  const float bias = bdw[ch];
  float m = -1e30f, sum = 0.f;
  for (int i = 0; i < 64; ++i) {
    int q = i * 256 + t;
    int n = q * 4;
    int d = n >> 12, h = (n >> 6) & 63, w0 = n & 63;
    float4 v = conv4(base, d, h, w0, cw);
    v.x += bias; v.y += bias; v.z += bias; v.w += bias;
    float vm = fmaxf(fmaxf(v.x, v.y), fmaxf(v.z, v.w));
    if (vm > m) { sum *= __expf(m - vm); m = vm; }
    sum += __expf(v.x - m) + __expf(v.y - m) + __expf(v.z - m) + __expf(v.w - m);
  }
  __shared__ float sm[256], sv[256];
  sm[t] = m; sv[t] = sum;
  __syncthreads();
  for (int o = 128; o > 0; o >>= 1) {
    if (t < o) {
      float m1 = sm[t], s1 = sv[t];
      float m2 = sm[t + o], s2 = sv[t + o];
      float mn = fmaxf(m1, m2);
      sm[t] = mn;
      sv[t] = s1 * __expf(m1 - mn) + s2 * __expf(m2 - mn);
    }
    __syncthreads();
  }
  if (t == 0) { rmax[b * SS + s] = sm[0]; rsum[b * SS + s] = sv[0]; }
}

// -------------------- K3: AB = softmax(conv(dt)) * conv(B_) ----------------
__global__ __launch_bounds__(256) void k_ab(const float* __restrict__ buf1,
                                            const float* __restrict__ Wdw,
                                            const float* __restrict__ bdw,
                                            const float* __restrict__ rmax,
                                            const float* __restrict__ rsum,
                                            float* __restrict__ AB) {
  const int chunk = blockIdx.x, s = blockIdx.y, b = blockIdx.z;
  const int t = threadIdx.x;
  const int chB = s, chD = 2 * SS + s;
  const float* baseB = buf1 + (size_t)(b * TS3 + chB) * NN;
  const float* baseD = buf1 + (size_t)(b * TS3 + chD) * NN;
  float cwB[27], cwD[27];
#pragma unroll
  for (int k = 0; k < 27; ++k) { cwB[k] = Wdw[chB * 27 + k]; cwD[k] = Wdw[chD * 27 + k]; }
  const float bB = bdw[chB], bD = bdw[chD];
  const float m = rmax[b * SS + s];
  const float inv = 1.f / rsum[b * SS + s];
  float* abp = AB + (size_t)(b * SS + s) * NN;
#pragma unroll
  for (int i = 0; i < 4; ++i) {
    int q = chunk * 1024 + i * 256 + t;
    int n = q * 4;
    int d = n >> 12, h = (n >> 6) & 63, w0 = n & 63;
    float4 vd = conv4(baseD, d, h, w0, cwD);
    float4 vb = conv4(baseB, d, h, w0, cwB);
    float4 o;
    o.x = __expf(vd.x + bD - m) * inv * (vb.x + bB);
    o.y = __expf(vd.y + bD - m) * inv * (vb.y + bB);
    o.z = __expf(vd.z + bD - m) * inv * (vb.z + bB);
    o.w = __expf(vd.w + bD - m) * inv * (vb.w + bB);
    *(float4*)(abp + n) = o;
  }
}

// -------------------- K4: h partials = x . AB^T (k-chunked) ----------------
// thread = (cq, sg): 4 c x 16 s accumulators. Partials land in the dead
// dt region of buf1 (b=0/1 areas), 512 slots x 16384 floats.
__global__ __launch_bounds__(256) void k_hgemm(const float* __restrict__ x,
                                               const float* __restrict__ AB,
                                               float* __restrict__ buf1) {
  __shared__ float xs[16][260];   // [k][c], stride 260 (16B-aligned, cf-free)
  __shared__ float abls[16][68];  // [k][s]
  const int chunk = blockIdx.x, b = blockIdx.y;
  const int t = threadIdx.x;
  const int cq = t & 63, sg = t >> 6;
  const float* xb = x + (size_t)b * CCH * NN;
  const float* abb = AB + (size_t)b * SS * NN;
  float acc[4][16];
#pragma unroll
  for (int j = 0; j < 4; ++j)
#pragma unroll
    for (int l = 0; l < 16; ++l) acc[j][l] = 0.f;
  for (int sub = 0; sub < 32; ++sub) {
    const int k0 = chunk * 512 + sub * 16;
#pragma unroll
    for (int i = 0; i < 4; ++i) {
      int f4 = t + i * 256;
      int c = f4 >> 2, k4 = f4 & 3;
      float4 v = *(const float4*)(xb + (size_t)c * NN + k0 + k4 * 4);
      xs[k4 * 4 + 0][c] = v.x; xs[k4 * 4 + 1][c] = v.y;
      xs[k4 * 4 + 2][c] = v.z; xs[k4 * 4 + 3][c] = v.w;
    }
    {
      int sA = t >> 2, k4 = t & 3;
      float4 v = *(const float4*)(abb + (size_t)sA * NN + k0 + k4 * 4);
      abls[k4 * 4 + 0][sA] = v.x; abls[k4 * 4 + 1][sA] = v.y;
      abls[k4 * 4 + 2][sA] = v.z; abls[k4 * 4 + 3][sA] = v.w;
    }
    __syncthreads();
#pragma unroll
    for (int k = 0; k < 16; ++k) {
      float4 xv = *(const float4*)&xs[k][cq * 4];
      const float* ar = &abls[k][sg * 16];
#pragma unroll
      for (int l = 0; l < 4; ++l) {
        float4 av = *(const float4*)&ar[l * 4];
        acc[0][l * 4 + 0] = fmaf(xv.x, av.x, acc[0][l * 4 + 0]);
        acc[1][l * 4 + 0] = fmaf(xv.y, av.x, acc[1][l * 4 + 0]);
        acc[2][l * 4 + 0] = fmaf(xv.z, av.x, acc[2][l * 4 + 0]);
        acc[3][l * 4 + 0] = fmaf(xv.w, av.x, acc[3][l * 4 + 0]);
        acc[0][l * 4 + 1] = fmaf(xv.x, av.y, acc[0][l * 4 + 1]);
        acc[1][l * 4 + 1] = fmaf(xv.y, av.y, acc[1][l * 4 + 1]);
        acc[2][l * 4 + 1] = fmaf(xv.z, av.y, acc[2][l * 4 + 1]);
        acc[3][l * 4 + 1] = fmaf(xv.w, av.y, acc[3][l * 4 + 1]);
        acc[0][l * 4 + 2] = fmaf(xv.x, av.z, acc[0][l * 4 + 2]);
        acc[1][l * 4 + 2] = fmaf(xv.y, av.z, acc[1][l * 4 + 2]);
        acc[2][l * 4 + 2] = fmaf(xv.z, av.z, acc[2][l * 4 + 2]);
        acc[3][l * 4 + 2] = fmaf(xv.w, av.z, acc[3][l * 4 + 2]);
        acc[0][l * 4 + 3] = fmaf(xv.x, av.w, acc[0][l * 4 + 3]);
        acc[1][l * 4 + 3] = fmaf(xv.y, av.w, acc[1][l * 4 + 3]);
        acc[2][l * 4 + 3] = fmaf(xv.z, av.w, acc[2][l * 4 + 3]);
        acc[3][l * 4 + 3] = fmaf(xv.w, av.w, acc[3][l * 4 + 3]);
      }
    }
    __syncthreads();
  }
  const int slot = chunk * 4 + b;
  float* pp = buf1 + (size_t)((slot >> 8) * TS3 + 128) * NN +
              (size_t)(slot & 255) * 16384;
#pragma unroll
  for (int j = 0; j < 4; ++j)
#pragma unroll
    for (int l = 0; l < 16; ++l)
      pp[(cq * 4 + j) * 64 + sg * 16 + l] = acc[j][l];
}

// -------------------- K4b: reduce partials -> h ----------------------------
__global__ __launch_bounds__(256) void k_hreduce(const float* __restrict__ buf1,
                                                 float* __restrict__ h) {
  int idx = blockIdx.x * 256 + threadIdx.x;
  int b = idx >> 14, cs = idx & 16383;
  float a0 = 0, a1 = 0, a2 = 0, a3 = 0;
  for (int c = 0; c < 128; c += 4) {
#pragma unroll
    for (int u = 0; u < 4; ++u) {
      int slot = (c + u) * 4 + b;
      const float* pp = buf1 + (size_t)((slot >> 8) * TS3 + 128) * NN +
                        (size_t)(slot & 255) * 16384;
      float v = pp[cs];
      if (u == 0) a0 += v; else if (u == 1) a1 += v; else if (u == 2) a2 += v; else a3 += v;
    }
  }
  h[idx] = (a0 + a1) + (a2 + a3);
}

// -------------------- K5: hz -> h3 -> h4 (small dense chain) ---------------
__global__ __launch_bounds__(256) void k_small(const float* __restrict__ h,
                                               const float* __restrict__ Whz,
                                               const float* __restrict__ bhz,
                                               const float* __restrict__ Wout,
                                               const float* __restrict__ bout,
                                               const float* __restrict__ Dp,
                                               float* __restrict__ h4out) {
  __shared__ float hs[256];
  __shared__ float h3s[256];
  const int s = blockIdx.x, b = blockIdx.y, t = threadIdx.x;
  hs[t] = h[(size_t)(b * CCH + t) * SS + s];
  __syncthreads();
  const float4* w0 = (const float4*)(Whz + (size_t)t * CCH);
  const float4* w1 = (const float4*)(Whz + (size_t)(t + 256) * CCH);
  float p0a = 0, p0b = 0, p0c = 0, p0d = 0, p1a = 0, p1b = 0, p1c = 0, p1d = 0;
#pragma unroll 8
  for (int c4 = 0; c4 < 64; ++c4) {
    float4 hv = *(const float4*)&hs[c4 * 4];
    float4 a = w0[c4], bq = w1[c4];
    p0a = fmaf(a.x, hv.x, p0a);  p0b = fmaf(a.y, hv.y, p0b);
    p0c = fmaf(a.z, hv.z, p0c);  p0d = fmaf(a.w, hv.w, p0d);
    p1a = fmaf(bq.x, hv.x, p1a); p1b = fmaf(bq.y, hv.y, p1b);
    p1c = fmaf(bq.z, hv.z, p1c); p1d = fmaf(bq.w, hv.w, p1d);
  }
  float h2 = (p0a + p0b) + (p0c + p0d) + bhz[t];
  float z  = (p1a + p1b) + (p1c + p1d) + bhz[t + 256];
  float sig = 1.f / (1.f + __expf(-z));
  float h3 = h2 * (z * sig) + h2 * Dp[0];
  h3s[t] = h3;
  __syncthreads();
  const float4* w2 = (const float4*)(Wout + (size_t)t * CCH);
  float q0 = 0, q1 = 0, q2 = 0, q3 = 0;
#pragma unroll 8
  for (int c4 = 0; c4 < 64; ++c4) {
    float4 hv = *(const float4*)&h3s[c4 * 4];
    float4 a = w2[c4];
    q0 = fmaf(a.x, hv.x, q0); q1 = fmaf(a.y, hv.y, q1);
    q2 = fmaf(a.z, hv.z, q2); q3 = fmaf(a.w, hv.w, q3);
  }
  h4out[(size_t)(b * CCH + t) * SS + s] = (q0 + q1) + (q2 + q3) + bout[t];
}

// -------------------- K6: y = h4 . conv(C_)  (conv fused) ------------------
__global__ __launch_bounds__(256) void k_y(const float* __restrict__ buf1,
                                           const float* __restrict__ Wdw,
                                           const float* __restrict__ bdw,
                                           const float* __restrict__ h4g,
                                           float* __restrict__ y) {
  __shared__ float Cc[64][64];   // [s][nl]
  __shared__ float h4s[64][64];  // [cl][s]
  const int b = blockIdx.y;
  const int n0 = blockIdx.x * 64;
  const int t = threadIdx.x;
#pragma unroll
  for (int i = 0; i < 4; ++i) {
    int q = t + i * 256;
    int sA = q >> 4, nq = q & 15;
    int ch = SS + sA;  // C_ band
    int n = n0 + nq * 4;
    int d = n >> 12, hh = (n >> 6) & 63, w0 = n & 63;
    const float* base = buf1 + (size_t)(b * TS3 + ch) * NN;
    float cw[27];
#pragma unroll
    for (int k = 0; k < 27; ++k) cw[k] = Wdw[ch * 27 + k];
    float4 v = conv4(base, d, hh, w0, cw);
    float bias = bdw[ch];
    Cc[sA][nq * 4 + 0] = v.x + bias;
    Cc[sA][nq * 4 + 1] = v.y + bias;
    Cc[sA][nq * 4 + 2] = v.z + bias;
    Cc[sA][nq * 4 + 3] = v.w + bias;
  }
  __syncthreads();
  const int cg = t >> 6, nl = t & 63;
  float creg[64];
#pragma unroll
  for (int sA = 0; sA < 64; ++sA) creg[sA] = Cc[sA][nl];
  for (int c0 = 0; c0 < CCH; c0 += 64) {
#pragma unroll
    for (int i = 0; i < 16; ++i) {
      int fl = t + i * 256;
      int cl = fl >> 6, sA = fl & 63;
      h4s[cl][sA] = h4g[(size_t)(b * CCH + c0 + cl) * SS + sA];
    }
    __syncthreads();
#pragma unroll
    for (int cl = 0; cl < 16; ++cl) {
      int cf = cg * 16 + cl;
      const float* hr = &h4s[cf][0];
      float a0 = 0, a1 = 0, a2 = 0, a3 = 0;
#pragma unroll
      for (int sq = 0; sq < 16; ++sq) {
        float4 hv = *(const float4*)&hr[sq * 4];
        a0 = fmaf(hv.x, creg[sq * 4 + 0], a0);
        a1 = fmaf(hv.y, creg[sq * 4 + 1], a1);
        a2 = fmaf(hv.z, creg[sq * 4 + 2], a2);
        a3 = fmaf(hv.w, creg[sq * 4 + 3], a3);
      }
      y[(size_t)(b * CCH + c0 + cf) * NN + n0 + nl] = (a0 + a1) + (a2 + a3);
    }
    __syncthreads();
  }
}

extern "C" void kernel_launch(void* const* d_in, const int* in_sizes, int n_in,
                              void* d_out, int out_size, void* d_ws, size_t ws_size,
                              hipStream_t stream) {
  (void)in_sizes; (void)n_in; (void)out_size; (void)ws_size;
  const float* x     = (const float*)d_in[0];
  const float* Wbcdt = (const float*)d_in[1];
  const float* bbcdt = (const float*)d_in[2];
  const float* Wdw   = (const float*)d_in[3];
  const float* bdw   = (const float*)d_in[4];
  const float* Whz   = (const float*)d_in[5];
  const float* bhz   = (const float*)d_in[6];
  const float* Wout  = (const float*)d_in[7];
  const float* bout  = (const float*)d_in[8];
  // d_in[9] = A: softmax shift-invariant per row -> unused.
  const float* Dp    = (const float*)d_in[10];
  float* out = (float*)d_out;
  float* ws  = (float*)d_ws;

  float* buf1 = ws;                  // 4*192*65536 f32 (201 MB)
  float* AB   = ws + OFF_AB;         // 4*64*65536 f32 (67 MB)
  float* rmax = ws + OFF_RMAX;
  float* rsum = ws + OFF_RSUM;
  float* h    = ws + OFF_H;
  float* h4o  = out + YTOT;          // h4 = 2nd output, also feeds k_y

  k_gemm1<<<dim3(1024, 4), 256, 0, stream>>>(x, Wbcdt, bbcdt, buf1);
  k_stats<<<dim3(64, 4), 256, 0, stream>>>(buf1, Wdw, bdw, rmax, rsum);
  k_ab<<<dim3(16, 64, 4), 256, 0, stream>>>(buf1, Wdw, bdw, rmax, rsum, AB);
  k_hgemm<<<dim3(128, 4), 256, 0, stream>>>(x, AB, buf1);
  k_hreduce<<<dim3(256), 256, 0, stream>>>(buf1, h);
  k_small<<<dim3(64, 4), 256, 0, stream>>>(h, Whz, bhz, Wout, bout, Dp, h4o);
  k_y<<<dim3(1024, 4), 256, 0, stream>>>(buf1, Wdw, bdw, h4o, out);
}

// Round 2
// 1350.904 us; speedup vs baseline: 1.7343x; 1.7343x over previous
//
#include <hip/hip_runtime.h>

// HSMSSD3D fused pipeline, bf16-MFMA version.
// B=4, C=256, S=64 (3S=192 ch), N = 16*64*64 = 65536.
//
//  k_castw   : W_bcdt -> bf16
//  k_gemm1   : BCdt_raw[b,192,N] = W@x + b   (MFMA; x transposed to LDS bf16)
//  k_stats   : rowwise softmax stats of conv(dt)+b_dw  (fp32, unchanged)
//  k_cc      : Cc_t[b,n,64] = bf16(conv(C_band)+bias)  (transposed for k_y)
//  k_ab      : AB[b,s,n] bf16 = softmax(conv(dt))*conv(B_)  -> C-band overlay
//  k_hgemm   : h^T partials = AB . x  (MFMA, split-K 128) -> B-band overlay
//  k_hreduce : ht[b,s,c] = sum partials
//  k_small   : hz -> h3 -> h4 (fp32 to d_out tail + bf16 copy)
//  k_y       : y = h4 . Cc   (MFMA, K=64)
//
// softmax(dt + A[s]) == softmax(dt)  -> A unused.

#define NN 65536
#define DD 16
#define HH 64
#define CCH 256
#define SS 64
#define TS3 192

#define YTOT 67108864ull  // y element count in d_out

typedef float f32x4 __attribute__((ext_vector_type(4)));
typedef short s16x8 __attribute__((ext_vector_type(8)));

__device__ __forceinline__ ushort f2bf(float f) {
  union { float f; unsigned u; } v; v.f = f;
  unsigned r = v.u + 0x7fffu + ((v.u >> 16) & 1u);
  return (ushort)(r >> 16);
}

// -------------------- 4-wide depthwise 3x3x3 conv helper --------------------
__device__ __forceinline__ float4 conv4(const float* __restrict__ base,
                                        int d, int h, int w0,
                                        const float* __restrict__ cw) {
  float ax = 0.f, ay = 0.f, az = 0.f, aw = 0.f;
#pragma unroll
  for (int kd = 0; kd < 3; ++kd) {
    int dd = d + kd - 1;
    if (dd < 0 || dd >= DD) continue;
#pragma unroll
    for (int kh = 0; kh < 3; ++kh) {
      int hh = h + kh - 1;
      if (hh < 0 || hh >= HH) continue;
      const float* row = base + dd * 4096 + hh * 64 + w0;
      float4 m = *(const float4*)row;
      float l = (w0 > 0) ? row[-1] : 0.f;
      float r = (w0 < 60) ? row[4] : 0.f;
      float c0 = cw[kd * 9 + kh * 3 + 0];
      float c1 = cw[kd * 9 + kh * 3 + 1];
      float c2 = cw[kd * 9 + kh * 3 + 2];
      ax = fmaf(c0, l,   fmaf(c1, m.x, fmaf(c2, m.y, ax)));
      ay = fmaf(c0, m.x, fmaf(c1, m.y, fmaf(c2, m.z, ay)));
      az = fmaf(c0, m.y, fmaf(c1, m.z, fmaf(c2, m.w, az)));
      aw = fmaf(c0, m.z, fmaf(c1, m.w, fmaf(c2, r,   aw)));
    }
  }
  return make_float4(ax, ay, az, aw);
}

// -------------------- W cast --------------------
__global__ void k_castw(const float* __restrict__ W, ushort* __restrict__ Wh, int n) {
  int i = blockIdx.x * 256 + threadIdx.x;
  if (i < n) Wh[i] = f2bf(W[i]);
}

// -------------------- K1: BCdt = W@x + b  (MFMA) --------------------
// Block: 64 n x 192 o, 4 waves (48 o each). x-tile (256c x 64n) transposed
// into LDS bf16 with XOR swizzle: elem (c,n) at xt[n*256 + ((c>>3 ^ (n&7))<<3) + (c&7)].
__global__ __launch_bounds__(256) void k_gemm1(const float* __restrict__ x,
                                               const ushort* __restrict__ Wh,
                                               const float* __restrict__ bb,
                                               float* __restrict__ out) {
  __shared__ ushort xt[64 * 256];
  const int t = threadIdx.x;
  const int b = blockIdx.y;
  const size_t n0 = (size_t)blockIdx.x * 64;
  const float* xb = x + (size_t)b * CCH * NN + n0;
  {
    const int g = t & 7, cb = t >> 3;  // 8 lanes/row cover 64 n; 32 rows/pass
#pragma unroll
    for (int p = 0; p < 8; ++p) {
      const int c = cb + p * 32;
      const float4 v0 = *(const float4*)(xb + (size_t)c * NN + g * 8);
      const float4 v1 = *(const float4*)(xb + (size_t)c * NN + g * 8 + 4);
      ushort u[8] = { f2bf(v0.x), f2bf(v0.y), f2bf(v0.z), f2bf(v0.w),
                      f2bf(v1.x), f2bf(v1.y), f2bf(v1.z), f2bf(v1.w) };
      const int chi = c >> 3, clo = c & 7;
#pragma unroll
      for (int j = 0; j < 8; ++j) {
        const int n = g * 8 + j;
        xt[n * 256 + ((chi ^ (n & 7)) << 3) + clo] = u[j];
      }
    }
  }
  __syncthreads();
  const int lane = t & 63, w = t >> 6;
  const int l15 = lane & 15, hi = lane >> 4;
  const int m0 = w * 48;
  f32x4 acc[3][4];
  const f32x4 zero = {0.f, 0.f, 0.f, 0.f};
#pragma unroll
  for (int mi = 0; mi < 3; ++mi)
#pragma unroll
    for (int ni = 0; ni < 4; ++ni) acc[mi][ni] = zero;
#pragma unroll
  for (int ks = 0; ks < 8; ++ks) {
    s16x8 a[3], bf[4];
#pragma unroll
    for (int mi = 0; mi < 3; ++mi)
      a[mi] = *(const s16x8*)(Wh + (size_t)(m0 + 16 * mi + l15) * 256 + ks * 32 + hi * 8);
#pragma unroll
    for (int ni = 0; ni < 4; ++ni) {
      const int n = 16 * ni + l15;
      const int gr = (ks * 4 + hi) ^ (n & 7);
      bf[ni] = *(const s16x8*)(&xt[n * 256 + gr * 8]);
    }
#pragma unroll
    for (int mi = 0; mi < 3; ++mi)
#pragma unroll
      for (int ni = 0; ni < 4; ++ni)
        acc[mi][ni] = __builtin_amdgcn_mfma_f32_16x16x32_bf16(a[mi], bf[ni], acc[mi][ni], 0, 0, 0);
  }
#pragma unroll
  for (int mi = 0; mi < 3; ++mi) {
#pragma unroll
    for (int r = 0; r < 4; ++r) {
      const int o = m0 + 16 * mi + hi * 4 + r;
      const float bias = bb[o];
      float* op = out + (size_t)(b * TS3 + o) * NN + n0;
#pragma unroll
      for (int ni = 0; ni < 4; ++ni)
        op[16 * ni + l15] = acc[mi][ni][r] + bias;
    }
  }
}

// -------------------- K2: softmax stats over conv(dt) ----------------------
__global__ __launch_bounds__(256) void k_stats(const float* __restrict__ buf1,
                                               const float* __restrict__ Wdw,
                                               const float* __restrict__ bdw,
                                               float* __restrict__ rmax,
                                               float* __restrict__ rsum) {
  const int s = blockIdx.x, b = blockIdx.y, t = threadIdx.x;
  const int ch = 2 * SS + s;
  const float* base = buf1 + (size_t)(b * TS3 + ch) * NN;
  float cw[27];
#pragma unroll
  for (int k = 0; k < 27; ++k) cw[k] = Wdw[ch * 27 + k];
  const float bias = bdw[ch];
  float m = -1e30f, sum = 0.f;
  for (int i = 0; i < 64; ++i) {
    int q = i * 256 + t;
    int n = q * 4;
    int d = n >> 12, h = (n >> 6) & 63, w0 = n & 63;
    float4 v = conv4(base, d, h, w0, cw);
    v.x += bias; v.y += bias; v.z += bias; v.w += bias;
    float vm = fmaxf(fmaxf(v.x, v.y), fmaxf(v.z, v.w));
    if (vm > m) { sum *= __expf(m - vm); m = vm; }
    sum += __expf(v.x - m) + __expf(v.y - m) + __expf(v.z - m) + __expf(v.w - m);
  }
  __shared__ float sm[256], sv[256];
  sm[t] = m; sv[t] = sum;
  __syncthreads();
  for (int o = 128; o > 0; o >>= 1) {
    if (t < o) {
      float m1 = sm[t], s1 = sv[t];
      float m2 = sm[t + o], s2 = sv[t + o];
      float mn = fmaxf(m1, m2);
      sm[t] = mn;
      sv[t] = s1 * __expf(m1 - mn) + s2 * __expf(m2 - mn);
    }
    __syncthreads();
  }
  if (t == 0) { rmax[b * SS + s] = sm[0]; rsum[b * SS + s] = sv[0]; }
}

// -------------------- K3: Cc_t[b][n][s] = bf16(conv(C_)+bias) --------------
__global__ __launch_bounds__(256) void k_cc(const float* __restrict__ buf1,
                                            const float* __restrict__ Wdw,
                                            const float* __restrict__ bdw,
                                            ushort* __restrict__ cct) {
  __shared__ ushort ct[256 * 68];
  const int t = threadIdx.x, b = blockIdx.y;
  const int nc = blockIdx.x;
  const int s = t & 63, ng = t >> 6;
  const int ch = SS + s;
  const float* base = buf1 + (size_t)(b * TS3 + ch) * NN;
  float cw[27];
#pragma unroll
  for (int k = 0; k < 27; ++k) cw[k] = Wdw[ch * 27 + k];
  const float bias = bdw[ch];
#pragma unroll
  for (int i = 0; i < 16; ++i) {
    const int nl = ng * 64 + i * 4;
    const int n = nc * 256 + nl;
    const int d = n >> 12, h = (n >> 6) & 63, w0 = n & 63;
    float4 v = conv4(base, d, h, w0, cw);
    ct[(nl + 0) * 68 + s] = f2bf(v.x + bias);
    ct[(nl + 1) * 68 + s] = f2bf(v.y + bias);
    ct[(nl + 2) * 68 + s] = f2bf(v.z + bias);
    ct[(nl + 3) * 68 + s] = f2bf(v.w + bias);
  }
  __syncthreads();
  ushort* cb = cct + ((size_t)b * NN + (size_t)nc * 256) * 64;
#pragma unroll
  for (int i = 0; i < 16; ++i) {
    const int f = t + i * 256;
    const int n = f >> 4, sseg = (f & 15) * 4;
    ushort4 v = *(const ushort4*)(&ct[n * 68 + sseg]);
    *(ushort4*)(cb + (size_t)n * 64 + sseg) = v;
  }
}

// -------------------- K4: AB bf16 = softmax(conv(dt)) * conv(B_) -----------
// Writes into the (now dead) C-band of buf1.
__global__ __launch_bounds__(256) void k_ab(float* buf1,
                                            const float* __restrict__ Wdw,
                                            const float* __restrict__ bdw,
                                            const float* __restrict__ rmax,
                                            const float* __restrict__ rsum) {
  const int chunk = blockIdx.x, s = blockIdx.y, b = blockIdx.z;
  const int t = threadIdx.x;
  const int chB = s, chD = 2 * SS + s;
  const float* baseB = buf1 + (size_t)(b * TS3 + chB) * NN;
  const float* baseD = buf1 + (size_t)(b * TS3 + chD) * NN;
  float cwB[27], cwD[27];
#pragma unroll
  for (int k = 0; k < 27; ++k) { cwB[k] = Wdw[chB * 27 + k]; cwD[k] = Wdw[chD * 27 + k]; }
  const float bB = bdw[chB], bD = bdw[chD];
  const float m = rmax[b * SS + s];
  const float inv = 1.f / rsum[b * SS + s];
  ushort* abw = (ushort*)(buf1 + (size_t)(b * TS3 + SS) * NN) + (size_t)s * NN;
#pragma unroll
  for (int i = 0; i < 4; ++i) {
    int q = chunk * 1024 + i * 256 + t;
    int n = q * 4;
    int d = n >> 12, h = (n >> 6) & 63, w0 = n & 63;
    float4 vd = conv4(baseD, d, h, w0, cwD);
    float4 vb = conv4(baseB, d, h, w0, cwB);
    ushort4 o;
    o.x = f2bf(__expf(vd.x + bD - m) * inv * (vb.x + bB));
    o.y = f2bf(__expf(vd.y + bD - m) * inv * (vb.y + bB));
    o.z = f2bf(__expf(vd.z + bD - m) * inv * (vb.z + bB));
    o.w = f2bf(__expf(vd.w + bD - m) * inv * (vb.w + bB));
    *(ushort4*)(abw + n) = o;
  }
}

// -------------------- K5: h^T partials = AB . x  (MFMA, split-K) -----------
// D[s][c] = sum_n AB[s][n] * x[c][n]; A=AB (n-contig), B=x cols (n-contig).
// Partials -> dead B-band of buf1: buf1[b*192*NN + chunk*16384 + s*256 + c].
__global__ __launch_bounds__(256) void k_hgemm(const float* __restrict__ x,
                                               float* buf1) {
  const int t = threadIdx.x, chunk = blockIdx.x, b = blockIdx.y;
  const int lane = t & 63, w = t >> 6;
  const int l15 = lane & 15, hi = lane >> 4;
  const ushort* abw = (const ushort*)(buf1 + (size_t)(b * TS3 + SS) * NN);
  const float* xb = x + (size_t)b * CCH * NN;
  const size_t k0 = (size_t)chunk * 512;
  f32x4 acc[4][4];
  const f32x4 zero = {0.f, 0.f, 0.f, 0.f};
#pragma unroll
  for (int mi = 0; mi < 4; ++mi)
#pragma unroll
    for (int ni = 0; ni < 4; ++ni) acc[mi][ni] = zero;
  for (int ks = 0; ks < 16; ++ks) {
    const size_t kk = k0 + ks * 32 + hi * 8;
    s16x8 a[4], bf[4];
#pragma unroll
    for (int mi = 0; mi < 4; ++mi)
      a[mi] = *(const s16x8*)(abw + (size_t)(16 * mi + l15) * NN + kk);
#pragma unroll
    for (int ni = 0; ni < 4; ++ni) {
      const int c = w * 64 + 16 * ni + l15;
      const float* xp = xb + (size_t)c * NN + kk;
      float4 v0 = *(const float4*)xp;
      float4 v1 = *(const float4*)(xp + 4);
      s16x8 bv = { (short)f2bf(v0.x), (short)f2bf(v0.y),
                   (short)f2bf(v0.z), (short)f2bf(v0.w),
                   (short)f2bf(v1.x), (short)f2bf(v1.y),
                   (short)f2bf(v1.z), (short)f2bf(v1.w) };
      bf[ni] = bv;
    }
#pragma unroll
    for (int mi = 0; mi < 4; ++mi)
#pragma unroll
      for (int ni = 0; ni < 4; ++ni)
        acc[mi][ni] = __builtin_amdgcn_mfma_f32_16x16x32_bf16(a[mi], bf[ni], acc[mi][ni], 0, 0, 0);
  }
  float* pp = buf1 + (size_t)b * TS3 * NN + (size_t)chunk * 16384;
#pragma unroll
  for (int mi = 0; mi < 4; ++mi)
#pragma unroll
    for (int r = 0; r < 4; ++r) {
      const int s = 16 * mi + hi * 4 + r;
#pragma unroll
      for (int ni = 0; ni < 4; ++ni)
        pp[s * 256 + w * 64 + 16 * ni + l15] = acc[mi][ni][r];
    }
}

// -------------------- K5b: reduce partials -> ht[b][s][c] ------------------
__global__ __launch_bounds__(256) void k_hreduce(const float* __restrict__ buf1,
                                                 float* __restrict__ ht) {
  const int idx = blockIdx.x * 256 + threadIdx.x;
  const int b = idx >> 14, sc = idx & 16383;
  const float* pb = buf1 + (size_t)b * TS3 * NN;
  float a0 = 0, a1 = 0, a2 = 0, a3 = 0;
  for (int ch = 0; ch < 128; ch += 4) {
    a0 += pb[(size_t)(ch + 0) * 16384 + sc];
    a1 += pb[(size_t)(ch + 1) * 16384 + sc];
    a2 += pb[(size_t)(ch + 2) * 16384 + sc];
    a3 += pb[(size_t)(ch + 3) * 16384 + sc];
  }
  ht[idx] = (a0 + a1) + (a2 + a3);
}

// -------------------- K6: hz -> h3 -> h4 -----------------------------------
__global__ __launch_bounds__(256) void k_small(const float* __restrict__ ht,
                                               const float* __restrict__ Whz,
                                               const float* __restrict__ bhz,
                                               const float* __restrict__ Wout,
                                               const float* __restrict__ bout,
                                               const float* __restrict__ Dp,
                                               float* __restrict__ h4out,
                                               ushort* __restrict__ h4h) {
  __shared__ float hs[256];
  __shared__ float h3s[256];
  const int s = blockIdx.x, b = blockIdx.y, t = threadIdx.x;
  hs[t] = ht[(size_t)b * 16384 + s * 256 + t];
  __syncthreads();
  const float4* w0 = (const float4*)(Whz + (size_t)t * CCH);
  const float4* w1 = (const float4*)(Whz + (size_t)(t + 256) * CCH);
  float p0a = 0, p0b = 0, p0c = 0, p0d = 0, p1a = 0, p1b = 0, p1c = 0, p1d = 0;
#pragma unroll 8
  for (int c4 = 0; c4 < 64; ++c4) {
    float4 hv = *(const float4*)&hs[c4 * 4];
    float4 a = w0[c4], bq = w1[c4];
    p0a = fmaf(a.x, hv.x, p0a);  p0b = fmaf(a.y, hv.y, p0b);
    p0c = fmaf(a.z, hv.z, p0c);  p0d = fmaf(a.w, hv.w, p0d);
    p1a = fmaf(bq.x, hv.x, p1a); p1b = fmaf(bq.y, hv.y, p1b);
    p1c = fmaf(bq.z, hv.z, p1c); p1d = fmaf(bq.w, hv.w, p1d);
  }
  float h2 = (p0a + p0b) + (p0c + p0d) + bhz[t];
  float z  = (p1a + p1b) + (p1c + p1d) + bhz[t + 256];
  float sig = 1.f / (1.f + __expf(-z));
  float h3 = h2 * (z * sig) + h2 * Dp[0];
  h3s[t] = h3;
  __syncthreads();
  const float4* w2 = (const float4*)(Wout + (size_t)t * CCH);
  float q0 = 0, q1 = 0, q2 = 0, q3 = 0;
#pragma unroll 8
  for (int c4 = 0; c4 < 64; ++c4) {
    float4 hv = *(const float4*)&h3s[c4 * 4];
    float4 a = w2[c4];
    q0 = fmaf(a.x, hv.x, q0); q1 = fmaf(a.y, hv.y, q1);
    q2 = fmaf(a.z, hv.z, q2); q3 = fmaf(a.w, hv.w, q3);
  }
  float h4v = (q0 + q1) + (q2 + q3) + bout[t];
  h4out[(size_t)(b * CCH + t) * SS + s] = h4v;
  h4h[(size_t)(b * CCH + t) * SS + s] = f2bf(h4v);
}

// -------------------- K7: y = h4 . Cc  (MFMA, K=64) ------------------------
__global__ __launch_bounds__(256) void k_y(const ushort* __restrict__ h4h,
                                           const ushort* __restrict__ cct,
                                           float* __restrict__ y) {
  const int t = threadIdx.x, b = blockIdx.y;
  const size_t n0 = (size_t)blockIdx.x * 64;
  const int lane = t & 63, w = t >> 6;
  const int l15 = lane & 15, hi = lane >> 4;
  const ushort* hb = h4h + (size_t)b * CCH * SS;
  const ushort* cb = cct + (size_t)b * NN * 64;
  f32x4 acc[4][4];
  const f32x4 zero = {0.f, 0.f, 0.f, 0.f};
#pragma unroll
  for (int mi = 0; mi < 4; ++mi)
#pragma unroll
    for (int ni = 0; ni < 4; ++ni) acc[mi][ni] = zero;
#pragma unroll
  for (int ks = 0; ks < 2; ++ks) {
    s16x8 a[4], bf[4];
#pragma unroll
    for (int mi = 0; mi < 4; ++mi) {
      const int c = w * 64 + 16 * mi + l15;
      a[mi] = *(const s16x8*)(hb + (size_t)c * 64 + ks * 32 + hi * 8);
    }
#pragma unroll
    for (int ni = 0; ni < 4; ++ni) {
      const size_t n = n0 + 16 * ni + l15;
      bf[ni] = *(const s16x8*)(cb + n * 64 + ks * 32 + hi * 8);
    }
#pragma unroll
    for (int mi = 0; mi < 4; ++mi)
#pragma unroll
      for (int ni = 0; ni < 4; ++ni)
        acc[mi][ni] = __builtin_amdgcn_mfma_f32_16x16x32_bf16(a[mi], bf[ni], acc[mi][ni], 0, 0, 0);
  }
#pragma unroll
  for (int mi = 0; mi < 4; ++mi)
#pragma unroll
    for (int r = 0; r < 4; ++r) {
      const int c = w * 64 + 16 * mi + hi * 4 + r;
      float* yp = y + (size_t)(b * CCH + c) * NN + n0;
#pragma unroll
      for (int ni = 0; ni < 4; ++ni)
        yp[16 * ni + l15] = acc[mi][ni][r];
    }
}

extern "C" void kernel_launch(void* const* d_in, const int* in_sizes, int n_in,
                              void* d_out, int out_size, void* d_ws, size_t ws_size,
                              hipStream_t stream) {
  (void)in_sizes; (void)n_in; (void)out_size; (void)ws_size;
  const float* x     = (const float*)d_in[0];
  const float* Wbcdt = (const float*)d_in[1];
  const float* bbcdt = (const float*)d_in[2];
  const float* Wdw   = (const float*)d_in[3];
  const float* bdw   = (const float*)d_in[4];
  const float* Whz   = (const float*)d_in[5];
  const float* bhz   = (const float*)d_in[6];
  const float* Wout  = (const float*)d_in[7];
  const float* bout  = (const float*)d_in[8];
  // d_in[9] = A: softmax shift-invariant -> unused.
  const float* Dp    = (const float*)d_in[10];
  float* out = (float*)d_out;
  float* ws  = (float*)d_ws;

  // ws layout (float slots):
  float*  buf1 = ws;                          // 50331648  (201 MB)
  ushort* cct  = (ushort*)(ws + 50331648ull); // 16777216 ush (33.5 MB)
  float*  ht   = ws + 58720256ull;            // 65536
  ushort* h4h  = (ushort*)(ws + 58785792ull); // 65536 ush
  ushort* Wh   = (ushort*)(ws + 58818560ull); // 49152 ush
  float*  rmax = ws + 58843136ull;            // 256
  float*  rsum = ws + 58843392ull;            // 256
  float*  h4o  = out + YTOT;

  k_castw<<<dim3(192), 256, 0, stream>>>(Wbcdt, Wh, TS3 * CCH);
  k_gemm1<<<dim3(1024, 4), 256, 0, stream>>>(x, Wh, bbcdt, buf1);
  k_stats<<<dim3(64, 4), 256, 0, stream>>>(buf1, Wdw, bdw, rmax, rsum);
  k_cc<<<dim3(256, 4), 256, 0, stream>>>(buf1, Wdw, bdw, cct);
  k_ab<<<dim3(16, 64, 4), 256, 0, stream>>>(buf1, Wdw, bdw, rmax, rsum);
  k_hgemm<<<dim3(128, 4), 256, 0, stream>>>(x, buf1);
  k_hreduce<<<dim3(256), 256, 0, stream>>>(buf1, ht);
  k_small<<<dim3(64, 4), 256, 0, stream>>>(ht, Whz, bhz, Wout, bout, Dp, h4o, h4h);
  k_y<<<dim3(1024, 4), 256, 0, stream>>>(h4h, cct, out);
}